// Round 1
// baseline (1854.723 us; speedup 1.0000x reference)
//
#include <hip/hip_runtime.h>
#include <math.h>

#define NROWS 8192
#define DIM   256
#define NCLS  64
#define KNN   5
#define NCAND 8      // per (row, j-split)
#define NSPLIT 4
#define MAXSTEPS 100

struct IterState {
  double Eold;
  int flag;       // converged
  int final_buf;  // parity of last-written Y buffer (0 = Ya, 1 = Yb)
};

// ---------------- wave (64-lane) reductions ----------------
__device__ __forceinline__ float wave_max64(float v) {
#pragma unroll
  for (int m = 32; m >= 1; m >>= 1) v = fmaxf(v, __shfl_xor(v, m, 64));
  return v;
}
__device__ __forceinline__ float wave_sum64(float v) {
#pragma unroll
  for (int m = 32; m >= 1; m >>= 1) v += __shfl_xor(v, m, 64);
  return v;
}
__device__ __forceinline__ double wave_sum64d(double v) {
#pragma unroll
  for (int m = 32; m >= 1; m >>= 1) v += __shfl_xor(v, m, 64);
  return v;
}

// ---------------- 1. row-normalize feats ----------------
__global__ void k_normalize(const float* __restrict__ feats, float* __restrict__ f,
                            double* __restrict__ sqd) {
  int row  = blockIdx.x * 4 + (threadIdx.x >> 6);
  int lane = threadIdx.x & 63;
  float4 v = ((const float4*)(feats + (size_t)row * DIM))[lane];
  double ss = (double)v.x * v.x + (double)v.y * v.y + (double)v.z * v.z + (double)v.w * v.w;
  ss = wave_sum64d(ss);
  float nrm = fmaxf((float)sqrt(ss), 1e-12f);
  float4 o;
  o.x = v.x / nrm; o.y = v.y / nrm; o.z = v.z / nrm; o.w = v.w / nrm;
  ((float4*)(f + (size_t)row * DIM))[lane] = o;
  // exact (fp64) squared norm of the ROUNDED fp32 normalized row -> used in refine keys
  double s2 = (double)o.x * o.x + (double)o.y * o.y + (double)o.z * o.z + (double)o.w * o.w;
  s2 = wave_sum64d(s2);
  if (lane == 0) sqd[row] = s2;
}

// ---------------- 2. fused Gram + per-row top-8 candidates ----------------
// grid = 512 blocks: (row-block 0..127) x (j-split 0..3). 64x64 LDS tiles,
// 4x4 micro-tile per thread, XOR-swizzled LDS (conflict-free fragment reads).
#define IT 64
#define JT 64
#define JSPAN (NROWS / NSPLIT)  // 2048

__device__ __forceinline__ int swz(int r, int c4) {
  return (r << 6) + (c4 ^ ((r ^ (r << 2)) & 7));
}

__launch_bounds__(256, 1)
__global__ void k_gram(const float* __restrict__ f, int* __restrict__ candp) {
  __shared__ float4 As4[IT * 64];  // 64 KiB
  __shared__ float4 Bs4[JT * 64];  // 64 KiB
  const int t  = threadIdx.x;
  const int ib = blockIdx.x >> 2;
  const int js = blockIdx.x & 3;
  const int i0 = ib * IT;
  const int jbase = js * JSPAN;

  // stage A (64 rows x 256 d), swizzled
#pragma unroll
  for (int r = 0; r < 16; ++r) {
    int e = t + 256 * r;
    int row = e >> 6, c4 = e & 63;
    float4 v = ((const float4*)(f + (size_t)(i0 + row) * DIM))[c4];
    As4[swz(row, c4)] = v;
  }

  const int ig = t >> 4;   // 0..15 -> 4 rows each
  const int jg = t & 15;   // 0..15 -> 4 cols each
  int abase[4], asw[4], bbase[4], bsw[4];
#pragma unroll
  for (int k = 0; k < 4; ++k) {
    int ra = ig * 4 + k; abase[k] = ra << 6; asw[k] = (ra ^ (ra << 2)) & 7;
    int rb = jg * 4 + k; bbase[k] = rb << 6; bsw[k] = (rb ^ (rb << 2)) & 7;
  }

  float bv[4][NCAND]; int bi[4][NCAND];
#pragma unroll
  for (int ii = 0; ii < 4; ++ii)
#pragma unroll
    for (int k = 0; k < NCAND; ++k) { bv[ii][k] = -1e30f; bi[ii][k] = -1; }

  for (int j0 = 0; j0 < JSPAN; j0 += JT) {
    __syncthreads();
#pragma unroll
    for (int r = 0; r < 16; ++r) {
      int e = t + 256 * r;
      int row = e >> 6, c4 = e & 63;
      float4 v = ((const float4*)(f + (size_t)(jbase + j0 + row) * DIM))[c4];
      Bs4[swz(row, c4)] = v;
    }
    __syncthreads();

    float acc[4][4];
#pragma unroll
    for (int ii = 0; ii < 4; ++ii)
#pragma unroll
      for (int jj = 0; jj < 4; ++jj) acc[ii][jj] = 0.f;

#pragma unroll 4
    for (int d4 = 0; d4 < 64; ++d4) {
      float4 b[4];
#pragma unroll
      for (int jj = 0; jj < 4; ++jj) b[jj] = Bs4[bbase[jj] + (d4 ^ bsw[jj])];
#pragma unroll
      for (int ii = 0; ii < 4; ++ii) {
        float4 a = As4[abase[ii] + (d4 ^ asw[ii])];
#pragma unroll
        for (int jj = 0; jj < 4; ++jj) {
          acc[ii][jj] = fmaf(a.x, b[jj].x,
                        fmaf(a.y, b[jj].y,
                        fmaf(a.z, b[jj].z,
                        fmaf(a.w, b[jj].w, acc[ii][jj]))));
        }
      }
    }

    // per-thread top-8 insert (sorted desc, bubble)
#pragma unroll
    for (int ii = 0; ii < 4; ++ii) {
#pragma unroll
      for (int jj = 0; jj < 4; ++jj) {
        float v = acc[ii][jj];
        int j = jbase + j0 + jg * 4 + jj;
        if (v > bv[ii][NCAND - 1]) {
          bv[ii][NCAND - 1] = v; bi[ii][NCAND - 1] = j;
#pragma unroll
          for (int k = NCAND - 1; k >= 1; --k) {
            if (bv[ii][k] > bv[ii][k - 1]) {
              float tv = bv[ii][k]; bv[ii][k] = bv[ii][k - 1]; bv[ii][k - 1] = tv;
              int ti = bi[ii][k]; bi[ii][k] = bi[ii][k - 1]; bi[ii][k - 1] = ti;
            }
          }
        }
      }
    }
  }

  // merge 16 per-thread lists per row -> top-8 per (row, split)
  __syncthreads();
  float* dv = (float*)As4;            // [64][128]
  int*   di = ((int*)As4) + IT * 128; // [64][128]
#pragma unroll
  for (int ii = 0; ii < 4; ++ii)
#pragma unroll
    for (int k = 0; k < NCAND; ++k) {
      int r = ig * 4 + ii;
      dv[r * 128 + jg * NCAND + k] = bv[ii][k];
      di[r * 128 + jg * NCAND + k] = bi[ii][k];
    }
  __syncthreads();
  if (t < IT) {
    float mv[NCAND]; int mi[NCAND];
#pragma unroll
    for (int k = 0; k < NCAND; ++k) { mv[k] = -1e30f; mi[k] = -1; }
    for (int s = 0; s < 128; ++s) {
      float v = dv[t * 128 + s]; int j = di[t * 128 + s];
      if (v > mv[NCAND - 1]) {
        mv[NCAND - 1] = v; mi[NCAND - 1] = j;
#pragma unroll
        for (int k = NCAND - 1; k >= 1; --k) {
          if (mv[k] > mv[k - 1]) {
            float tv = mv[k]; mv[k] = mv[k - 1]; mv[k - 1] = tv;
            int ti = mi[k]; mi[k] = mi[k - 1]; mi[k - 1] = ti;
          }
        }
      }
    }
#pragma unroll
    for (int k = 0; k < NCAND; ++k)
      candp[(size_t)js * (NROWS * NCAND) + (size_t)(i0 + t) * NCAND + k] = mi[k];
  }
}

// ---------------- 3. fp64 exact refine: 32 candidates -> exact top-5 ----------------
__global__ void k_refine(const float* __restrict__ f, const double* __restrict__ sqd,
                         const int* __restrict__ candp, int* __restrict__ nbr) {
  const int row = blockIdx.x;
  const int t = threadIdx.x;   // 64 threads
  const int c = t >> 1;        // candidate 0..31
  const int seg = t & 1;       // half of D
  const int split = c >> 3, slot = c & 7;
  int j = candp[(size_t)split * (NROWS * NCAND) + (size_t)row * NCAND + slot];
  const float* fi = f + (size_t)row * DIM;
  const float* fj = f + (size_t)j * DIM;
  double dot = 0.0;
  const int dbase = seg * 128;
#pragma unroll 4
  for (int d = 0; d < 128; ++d)
    dot = fma((double)fi[dbase + d], (double)fj[dbase + d], dot);
  dot += __shfl_xor(dot, 1, 64);
  double key = sqd[j] - 2.0 * dot;   // == dist2 - sq_i (monotone in dist)
  bool valid = (seg == 0) && (j != row);   // exclude self (== reference's idx[:,1:])
  for (int s = 0; s < KNN; ++s) {
    double v = valid ? key : (double)INFINITY;
    int vj = valid ? j : 0x7fffffff;
#pragma unroll
    for (int m = 1; m < 64; m <<= 1) {
      double ov = __shfl_xor(v, m, 64);
      int oj = __shfl_xor(vj, m, 64);
      if (ov < v || (ov == v && oj < vj)) { v = ov; vj = oj; }
    }
    if (valid && vj == j) valid = false;
    if (t == 0) nbr[(size_t)row * 8 + s] = vj;
  }
}

// ---------------- 4. unary + Y0 ----------------
__global__ void k_inity(const float* __restrict__ scores, float* __restrict__ unary,
                        float* __restrict__ Y) {
  int row = blockIdx.x * 4 + (threadIdx.x >> 6);
  int c = threadIdx.x & 63;
  float s = scores[(size_t)row * NCLS + c];
  float u = -logf(s + 1e-10f);
  unary[(size_t)row * NCLS + c] = u;
  float logit = -u;
  float m = wave_max64(logit);
  float e = expf(logit - m);
  float sum = wave_sum64(e);
  Y[(size_t)row * NCLS + c] = e / sum;
}

// ---------------- 5. one mean-field iteration (+ per-block energy partial) ----------------
// E = sum(u*Y - pw*Y + Y*logY) collapses to -sum_rows lse (LAM == 1).
__global__ void k_iter(const float* __restrict__ Yin, float* __restrict__ Yout,
                       const float* __restrict__ unary, const int* __restrict__ nbr,
                       const IterState* __restrict__ st, double* __restrict__ Epart) {
  if (st->flag) return;
  int w = threadIdx.x >> 6;
  int row = blockIdx.x * 4 + w;
  int c = threadIdx.x & 63;
  const int* nb = nbr + (size_t)row * 8;
  float pw = 0.f;
#pragma unroll
  for (int k = 0; k < KNN; ++k) pw += Yin[(size_t)nb[k] * NCLS + c];
  float logit = pw - unary[(size_t)row * NCLS + c];
  float m = wave_max64(logit);
  float e = expf(logit - m);
  float sum = wave_sum64(e);
  Yout[(size_t)row * NCLS + c] = e / sum;
  __shared__ double sE[4];
  if (c == 0) sE[w] = -(double)(m + logf(sum));
  __syncthreads();
  if (threadIdx.x == 0) Epart[blockIdx.x] = (sE[0] + sE[1]) + (sE[2] + sE[3]);
}

// ---------------- 6. convergence check ----------------
__global__ void k_check(IterState* st, const double* __restrict__ Epart, int iter) {
  if (st->flag) return;
  __shared__ double sd[256];
  double s = 0.0;
  for (int i = threadIdx.x; i < NROWS / 4; i += 256) s += Epart[i];
  sd[threadIdx.x] = s;
  __syncthreads();
  for (int off = 128; off >= 1; off >>= 1) {
    if (threadIdx.x < off) sd[threadIdx.x] += sd[threadIdx.x + off];
    __syncthreads();
  }
  if (threadIdx.x == 0) {
    double E = sd[0];
    bool conv = (iter > 1) && (fabs(E - st->Eold) <= 1e-8 * fabs(st->Eold));
    st->final_buf = (iter + 1) & 1;  // iter wrote buf[(iter+1)&1]
    if (conv) st->flag = 1;
    else st->Eold = E;
  }
}

// ---------------- 0/7. state init + final copy ----------------
__global__ void k_init(IterState* st) {
  st->Eold = (double)INFINITY; st->flag = 0; st->final_buf = 0;
}
__global__ void k_copy(const float* __restrict__ Ya, const float* __restrict__ Yb,
                       const IterState* __restrict__ st, float* __restrict__ out) {
  const float* src = st->final_buf ? Yb : Ya;
  int i = blockIdx.x * blockDim.x + threadIdx.x;
  ((float4*)out)[i] = ((const float4*)src)[i];
}

extern "C" void kernel_launch(void* const* d_in, const int* in_sizes, int n_in,
                              void* d_out, int out_size, void* d_ws, size_t ws_size,
                              hipStream_t stream) {
  (void)in_sizes; (void)n_in; (void)out_size; (void)ws_size;
  const float* scores = (const float*)d_in[0];
  const float* feats  = (const float*)d_in[1];
  float* out = (float*)d_out;
  char* ws = (char*)d_ws;
  // workspace layout (all 256B-aligned); total ~16.1 MB
  float*  f     = (float*)(ws + 0);          //  8 MB
  float*  Ya    = (float*)(ws + 8388608);    //  2 MB
  float*  Yb    = (float*)(ws + 10485760);   //  2 MB
  float*  unary = (float*)(ws + 12582912);   //  2 MB
  double* sqd   = (double*)(ws + 14680064);  // 64 KB
  int*    candp = (int*)(ws + 14745600);     //  1 MB (4 splits x 8192 x 8)
  int*    nbr   = (int*)(ws + 15794176);     // 256 KB
  double* Epart = (double*)(ws + 16056320);  // 16 KB
  IterState* st = (IterState*)(ws + 16072704);

  k_init<<<1, 1, 0, stream>>>(st);
  k_normalize<<<NROWS / 4, 256, 0, stream>>>(feats, f, sqd);
  k_gram<<<(NROWS / IT) * NSPLIT, 256, 0, stream>>>(f, candp);
  k_refine<<<NROWS, 64, 0, stream>>>(f, sqd, candp, nbr);
  k_inity<<<NROWS / 4, 256, 0, stream>>>(scores, unary, Ya);
  for (int k = 0; k < MAXSTEPS; ++k) {
    const float* yin = (k & 1) ? Yb : Ya;
    float* yout = (k & 1) ? Ya : Yb;
    k_iter<<<NROWS / 4, 256, 0, stream>>>(yin, yout, unary, nbr, st, Epart);
    k_check<<<1, 256, 0, stream>>>(st, Epart, k);
  }
  k_copy<<<512, 256, 0, stream>>>(Ya, Yb, st, out);
}

// Round 2
// 1449.637 us; speedup vs baseline: 1.2794x; 1.2794x over previous
//
#include <hip/hip_runtime.h>
#include <math.h>

#define NROWS 8192
#define DIM   256
#define NCLS  64
#define KNN   5
#define NCAND 8      // per (row, j-split)
#define NSPLIT 4
#define MAXSTEPS 100

struct IterState {
  double Eold;
  int flag;       // converged
  int final_buf;  // parity of last-written Y buffer (0 = Ya, 1 = Yb)
};

// ---------------- wave (64-lane) reductions ----------------
__device__ __forceinline__ float wave_max64(float v) {
#pragma unroll
  for (int m = 32; m >= 1; m >>= 1) v = fmaxf(v, __shfl_xor(v, m, 64));
  return v;
}
__device__ __forceinline__ float wave_sum64(float v) {
#pragma unroll
  for (int m = 32; m >= 1; m >>= 1) v += __shfl_xor(v, m, 64);
  return v;
}
__device__ __forceinline__ double wave_sum64d(double v) {
#pragma unroll
  for (int m = 32; m >= 1; m >>= 1) v += __shfl_xor(v, m, 64);
  return v;
}

// ---------------- 1. row-normalize feats ----------------
__global__ void k_normalize(const float* __restrict__ feats, float* __restrict__ f,
                            double* __restrict__ sqd) {
  int row  = blockIdx.x * 4 + (threadIdx.x >> 6);
  int lane = threadIdx.x & 63;
  float4 v = ((const float4*)(feats + (size_t)row * DIM))[lane];
  double ss = (double)v.x * v.x + (double)v.y * v.y + (double)v.z * v.z + (double)v.w * v.w;
  ss = wave_sum64d(ss);
  float nrm = fmaxf((float)sqrt(ss), 1e-12f);
  float4 o;
  o.x = v.x / nrm; o.y = v.y / nrm; o.z = v.z / nrm; o.w = v.w / nrm;
  ((float4*)(f + (size_t)row * DIM))[lane] = o;
  // exact (fp64) squared norm of the ROUNDED fp32 normalized row -> used in refine keys
  double s2 = (double)o.x * o.x + (double)o.y * o.y + (double)o.z * o.z + (double)o.w * o.w;
  s2 = wave_sum64d(s2);
  if (lane == 0) sqd[row] = s2;
}

// ---------------- 2. fused Gram + per-row top-8 candidates ----------------
// grid = 512 blocks: (row-block 0..127) x (j-split 0..3). 64x64 LDS tiles,
// 4x4 micro-tile per thread.
// Swizzle: idx = r*64 + (c4 ^ ((r>>2)&7)).  For B-fragment reads rb>>2 == jg,
// so the 16 distinct per-wave addresses land on 8 bank-groups (2-way = free);
// A-fragment reads: 4 addresses on 4 groups (conflict-free); staging writes
// conflict-free (row constant per wave, c4 spans 0..63).
#define IT 64
#define JT 64
#define JSPAN (NROWS / NSPLIT)  // 2048

__device__ __forceinline__ int swz(int r, int c4) {
  return (r << 6) + (c4 ^ ((r >> 2) & 7));
}

__launch_bounds__(256, 1)
__global__ void k_gram(const float* __restrict__ f, int* __restrict__ candp) {
  __shared__ float4 As4[IT * 64];  // 64 KiB
  __shared__ float4 Bs4[JT * 64];  // 64 KiB
  const int t  = threadIdx.x;
  const int ib = blockIdx.x >> 2;
  const int js = blockIdx.x & 3;
  const int i0 = ib * IT;
  const int jbase = js * JSPAN;

  // stage A (64 rows x 256 d), swizzled
#pragma unroll
  for (int r = 0; r < 16; ++r) {
    int e = t + 256 * r;
    int row = e >> 6, c4 = e & 63;
    float4 v = ((const float4*)(f + (size_t)(i0 + row) * DIM))[c4];
    As4[swz(row, c4)] = v;
  }

  const int ig = t >> 4;   // 0..15 -> 4 rows each
  const int jg = t & 15;   // 0..15 -> 4 cols each
  // ra = ig*4+k -> ra>>2 == ig; rb = jg*4+k -> rb>>2 == jg
  const int asw = ig & 7;
  const int bsw = jg & 7;
  int abase[4], bbase[4];
#pragma unroll
  for (int k = 0; k < 4; ++k) {
    abase[k] = (ig * 4 + k) << 6;
    bbase[k] = (jg * 4 + k) << 6;
  }

  float bv[4][NCAND]; int bi[4][NCAND];
#pragma unroll
  for (int ii = 0; ii < 4; ++ii)
#pragma unroll
    for (int k = 0; k < NCAND; ++k) { bv[ii][k] = -1e30f; bi[ii][k] = -1; }

  for (int j0 = 0; j0 < JSPAN; j0 += JT) {
    __syncthreads();
#pragma unroll
    for (int r = 0; r < 16; ++r) {
      int e = t + 256 * r;
      int row = e >> 6, c4 = e & 63;
      float4 v = ((const float4*)(f + (size_t)(jbase + j0 + row) * DIM))[c4];
      Bs4[swz(row, c4)] = v;
    }
    __syncthreads();

    float acc[4][4];
#pragma unroll
    for (int ii = 0; ii < 4; ++ii)
#pragma unroll
      for (int jj = 0; jj < 4; ++jj) acc[ii][jj] = 0.f;

#pragma unroll 4
    for (int d4 = 0; d4 < 64; ++d4) {
      float4 b[4];
#pragma unroll
      for (int jj = 0; jj < 4; ++jj) b[jj] = Bs4[bbase[jj] + (d4 ^ bsw)];
#pragma unroll
      for (int ii = 0; ii < 4; ++ii) {
        float4 a = As4[abase[ii] + (d4 ^ asw)];
#pragma unroll
        for (int jj = 0; jj < 4; ++jj) {
          acc[ii][jj] = fmaf(a.x, b[jj].x,
                        fmaf(a.y, b[jj].y,
                        fmaf(a.z, b[jj].z,
                        fmaf(a.w, b[jj].w, acc[ii][jj]))));
        }
      }
    }

    // per-thread top-8 insert (sorted desc, bubble)
#pragma unroll
    for (int ii = 0; ii < 4; ++ii) {
#pragma unroll
      for (int jj = 0; jj < 4; ++jj) {
        float v = acc[ii][jj];
        int j = jbase + j0 + jg * 4 + jj;
        if (v > bv[ii][NCAND - 1]) {
          bv[ii][NCAND - 1] = v; bi[ii][NCAND - 1] = j;
#pragma unroll
          for (int k = NCAND - 1; k >= 1; --k) {
            if (bv[ii][k] > bv[ii][k - 1]) {
              float tv = bv[ii][k]; bv[ii][k] = bv[ii][k - 1]; bv[ii][k - 1] = tv;
              int ti = bi[ii][k]; bi[ii][k] = bi[ii][k - 1]; bi[ii][k - 1] = ti;
            }
          }
        }
      }
    }
  }

  // merge 16 per-thread lists per row -> top-8 per (row, split)
  // padded stride 130 avoids the single-bank column pattern in the merge loop
  __syncthreads();
  float* dv = (float*)As4;             // [64][130]
  int*   di = ((int*)As4) + IT * 130;  // [64][130]
#pragma unroll
  for (int ii = 0; ii < 4; ++ii)
#pragma unroll
    for (int k = 0; k < NCAND; ++k) {
      int r = ig * 4 + ii;
      dv[r * 130 + jg * NCAND + k] = bv[ii][k];
      di[r * 130 + jg * NCAND + k] = bi[ii][k];
    }
  __syncthreads();
  if (t < IT) {
    float mv[NCAND]; int mi[NCAND];
#pragma unroll
    for (int k = 0; k < NCAND; ++k) { mv[k] = -1e30f; mi[k] = -1; }
    for (int s = 0; s < 128; ++s) {
      float v = dv[t * 130 + s]; int j = di[t * 130 + s];
      if (v > mv[NCAND - 1]) {
        mv[NCAND - 1] = v; mi[NCAND - 1] = j;
#pragma unroll
        for (int k = NCAND - 1; k >= 1; --k) {
          if (mv[k] > mv[k - 1]) {
            float tv = mv[k]; mv[k] = mv[k - 1]; mv[k - 1] = tv;
            int ti = mi[k]; mi[k] = mi[k - 1]; mi[k - 1] = ti;
          }
        }
      }
    }
#pragma unroll
    for (int k = 0; k < NCAND; ++k)
      candp[(size_t)js * (NROWS * NCAND) + (size_t)(i0 + t) * NCAND + k] = mi[k];
  }
}

// ---------------- 3. fp64 exact refine: 32 candidates -> exact top-5 ----------------
__global__ void k_refine(const float* __restrict__ f, const double* __restrict__ sqd,
                         const int* __restrict__ candp, int* __restrict__ nbr) {
  const int row = blockIdx.x;
  const int t = threadIdx.x;   // 64 threads
  const int c = t >> 1;        // candidate 0..31
  const int seg = t & 1;       // half of D
  const int split = c >> 3, slot = c & 7;
  int j = candp[(size_t)split * (NROWS * NCAND) + (size_t)row * NCAND + slot];
  const float* fi = f + (size_t)row * DIM;
  const float* fj = f + (size_t)j * DIM;
  double dot = 0.0;
  const int dbase = seg * 128;
#pragma unroll 4
  for (int d = 0; d < 128; ++d)
    dot = fma((double)fi[dbase + d], (double)fj[dbase + d], dot);
  dot += __shfl_xor(dot, 1, 64);
  double key = sqd[j] - 2.0 * dot;   // == dist2 - sq_i (monotone in dist)
  bool valid = (seg == 0) && (j != row);   // exclude self (== reference's idx[:,1:])
  for (int s = 0; s < KNN; ++s) {
    double v = valid ? key : (double)INFINITY;
    int vj = valid ? j : 0x7fffffff;
#pragma unroll
    for (int m = 1; m < 64; m <<= 1) {
      double ov = __shfl_xor(v, m, 64);
      int oj = __shfl_xor(vj, m, 64);
      if (ov < v || (ov == v && oj < vj)) { v = ov; vj = oj; }
    }
    if (valid && vj == j) valid = false;
    if (t == 0) nbr[(size_t)row * 8 + s] = vj;
  }
}

// ---------------- 4. unary + Y0 ----------------
__global__ void k_inity(const float* __restrict__ scores, float* __restrict__ unary,
                        float* __restrict__ Y) {
  int row = blockIdx.x * 4 + (threadIdx.x >> 6);
  int c = threadIdx.x & 63;
  float s = scores[(size_t)row * NCLS + c];
  float u = -logf(s + 1e-10f);
  unary[(size_t)row * NCLS + c] = u;
  float logit = -u;
  float m = wave_max64(logit);
  float e = expf(logit - m);
  float sum = wave_sum64(e);
  Y[(size_t)row * NCLS + c] = e / sum;
}

// ---------------- 5. one mean-field iteration (+ per-block energy partial) ----------------
// E = sum(u*Y - pw*Y + Y*logY) collapses to -sum_rows lse (LAM == 1).
__global__ void k_iter(const float* __restrict__ Yin, float* __restrict__ Yout,
                       const float* __restrict__ unary, const int* __restrict__ nbr,
                       const IterState* __restrict__ st, double* __restrict__ Epart) {
  if (st->flag) return;
  int w = threadIdx.x >> 6;
  int row = blockIdx.x * 4 + w;
  int c = threadIdx.x & 63;
  const int* nb = nbr + (size_t)row * 8;
  float pw = 0.f;
#pragma unroll
  for (int k = 0; k < KNN; ++k) pw += Yin[(size_t)nb[k] * NCLS + c];
  float logit = pw - unary[(size_t)row * NCLS + c];
  float m = wave_max64(logit);
  float e = expf(logit - m);
  float sum = wave_sum64(e);
  Yout[(size_t)row * NCLS + c] = e / sum;
  __shared__ double sE[4];
  if (c == 0) sE[w] = -(double)(m + logf(sum));
  __syncthreads();
  if (threadIdx.x == 0) Epart[blockIdx.x] = (sE[0] + sE[1]) + (sE[2] + sE[3]);
}

// ---------------- 6. convergence check ----------------
__global__ void k_check(IterState* st, const double* __restrict__ Epart, int iter) {
  if (st->flag) return;
  __shared__ double sd[256];
  double s = 0.0;
  for (int i = threadIdx.x; i < NROWS / 4; i += 256) s += Epart[i];
  sd[threadIdx.x] = s;
  __syncthreads();
  for (int off = 128; off >= 1; off >>= 1) {
    if (threadIdx.x < off) sd[threadIdx.x] += sd[threadIdx.x + off];
    __syncthreads();
  }
  if (threadIdx.x == 0) {
    double E = sd[0];
    bool conv = (iter > 1) && (fabs(E - st->Eold) <= 1e-8 * fabs(st->Eold));
    st->final_buf = (iter + 1) & 1;  // iter wrote buf[(iter+1)&1]
    if (conv) st->flag = 1;
    else st->Eold = E;
  }
}

// ---------------- 0/7. state init + final copy ----------------
__global__ void k_init(IterState* st) {
  st->Eold = (double)INFINITY; st->flag = 0; st->final_buf = 0;
}
__global__ void k_copy(const float* __restrict__ Ya, const float* __restrict__ Yb,
                       const IterState* __restrict__ st, float* __restrict__ out) {
  const float* src = st->final_buf ? Yb : Ya;
  int i = blockIdx.x * blockDim.x + threadIdx.x;
  ((float4*)out)[i] = ((const float4*)src)[i];
}

extern "C" void kernel_launch(void* const* d_in, const int* in_sizes, int n_in,
                              void* d_out, int out_size, void* d_ws, size_t ws_size,
                              hipStream_t stream) {
  (void)in_sizes; (void)n_in; (void)out_size; (void)ws_size;
  const float* scores = (const float*)d_in[0];
  const float* feats  = (const float*)d_in[1];
  float* out = (float*)d_out;
  char* ws = (char*)d_ws;
  // workspace layout (all 256B-aligned); total ~16.1 MB
  float*  f     = (float*)(ws + 0);          //  8 MB
  float*  Ya    = (float*)(ws + 8388608);    //  2 MB
  float*  Yb    = (float*)(ws + 10485760);   //  2 MB
  float*  unary = (float*)(ws + 12582912);   //  2 MB
  double* sqd   = (double*)(ws + 14680064);  // 64 KB
  int*    candp = (int*)(ws + 14745600);     //  1 MB (4 splits x 8192 x 8)
  int*    nbr   = (int*)(ws + 15794176);     // 256 KB
  double* Epart = (double*)(ws + 16056320);  // 16 KB
  IterState* st = (IterState*)(ws + 16072704);

  k_init<<<1, 1, 0, stream>>>(st);
  k_normalize<<<NROWS / 4, 256, 0, stream>>>(feats, f, sqd);
  k_gram<<<(NROWS / IT) * NSPLIT, 256, 0, stream>>>(f, candp);
  k_refine<<<NROWS, 64, 0, stream>>>(f, sqd, candp, nbr);
  k_inity<<<NROWS / 4, 256, 0, stream>>>(scores, unary, Ya);
  for (int k = 0; k < MAXSTEPS; ++k) {
    const float* yin = (k & 1) ? Yb : Ya;
    float* yout = (k & 1) ? Ya : Yb;
    k_iter<<<NROWS / 4, 256, 0, stream>>>(yin, yout, unary, nbr, st, Epart);
    k_check<<<1, 256, 0, stream>>>(st, Epart, k);
  }
  k_copy<<<512, 256, 0, stream>>>(Ya, Yb, st, out);
}

// Round 3
// 632.085 us; speedup vs baseline: 2.9343x; 2.2934x over previous
//
#include <hip/hip_runtime.h>
#include <math.h>

#define NROWS 8192
#define DIM   256
#define NCLS  64
#define KNN   5
#define NCAND 8      // per (row, j-split)
#define NSPLIT 4
#define MAXSTEPS 100
#define ITER_GRID 512

struct IterState {
  double Eold;
  int flag;       // converged
  int final_buf;  // parity of last-written Y buffer (0 = Ya, 1 = Yb)
};

typedef __attribute__((ext_vector_type(8))) short bf16x8;
typedef __attribute__((ext_vector_type(4))) float f32x4;

// ---------------- wave (64-lane) reductions ----------------
__device__ __forceinline__ float wave_max64(float v) {
#pragma unroll
  for (int m = 32; m >= 1; m >>= 1) v = fmaxf(v, __shfl_xor(v, m, 64));
  return v;
}
__device__ __forceinline__ float wave_sum64(float v) {
#pragma unroll
  for (int m = 32; m >= 1; m >>= 1) v += __shfl_xor(v, m, 64);
  return v;
}
__device__ __forceinline__ double wave_sum64d(double v) {
#pragma unroll
  for (int m = 32; m >= 1; m >>= 1) v += __shfl_xor(v, m, 64);
  return v;
}

__device__ __forceinline__ unsigned short f2bf(float x) {  // RNE bf16
  unsigned u = __float_as_uint(x);
  u += 0x7FFFu + ((u >> 16) & 1u);
  return (unsigned short)(u >> 16);
}
__device__ __forceinline__ uint4 pack8(float4 a, float4 b) {
  uint4 r;
  r.x = (unsigned)f2bf(a.x) | ((unsigned)f2bf(a.y) << 16);
  r.y = (unsigned)f2bf(a.z) | ((unsigned)f2bf(a.w) << 16);
  r.z = (unsigned)f2bf(b.x) | ((unsigned)f2bf(b.y) << 16);
  r.w = (unsigned)f2bf(b.z) | ((unsigned)f2bf(b.w) << 16);
  return r;
}

// ---------------- 1. row-normalize feats ----------------
__global__ void k_normalize(const float* __restrict__ feats, float* __restrict__ f,
                            double* __restrict__ sqd) {
  int row  = blockIdx.x * 4 + (threadIdx.x >> 6);
  int lane = threadIdx.x & 63;
  float4 v = ((const float4*)(feats + (size_t)row * DIM))[lane];
  double ss = (double)v.x * v.x + (double)v.y * v.y + (double)v.z * v.z + (double)v.w * v.w;
  ss = wave_sum64d(ss);
  float nrm = fmaxf((float)sqrt(ss), 1e-12f);
  float4 o;
  o.x = v.x / nrm; o.y = v.y / nrm; o.z = v.z / nrm; o.w = v.w / nrm;
  ((float4*)(f + (size_t)row * DIM))[lane] = o;
  // exact (fp64) squared norm of the ROUNDED fp32 normalized row -> refine keys
  double s2 = (double)o.x * o.x + (double)o.y * o.y + (double)o.z * o.z + (double)o.w * o.w;
  s2 = wave_sum64d(s2);
  if (lane == 0) sqd[row] = s2;
}

// ---------------- 2. MFMA bf16 candidate Gram + per-row top-8 ----------------
// grid = 512 blocks: (row-block ib 0..127) x (j-split js 0..3).
// Per block: A-tile 64 rows x 256 dims bf16 (32 KB, staged once, XOR-swizzled),
// loop over 32 j-tiles of 64 cols: stage B (32 KB, prefetched in regs during
// MFMA of previous tile), 4 waves x (2x2 of 16x16x32 bf16 MFMA) -> 64x64 C,
// C -> swizzled LDS (16 KB) -> per-thread top-8 over 16-col segment -> merge.
// Swizzle (A/B): 16B granule g of row r stored at slot g ^ (r & 31):
//   frag reads + staging writes both land exactly 8 word-hits/bank (balanced).
// Swizzle (C): granule gc of row r at gc ^ (r & 15): writes 2-way (free),
//   reads balanced.
#define JSPAN (NROWS / NSPLIT)  // 2048

__launch_bounds__(256, 2)
__global__ void k_gram(const float* __restrict__ f, int* __restrict__ candp) {
  __shared__ unsigned short Ash[64 * 256];  // 32 KB bf16, swizzled granules
  __shared__ unsigned short Bsh[64 * 256];  // 32 KB
  __shared__ float Csh[64 * 64];            // 16 KB (reused as merge area)

  const int t  = threadIdx.x;
  const int ib = blockIdx.x >> 2;
  const int js = blockIdx.x & 3;
  const int i0 = ib * 64;
  const int jbase = js * JSPAN;

  // ---- stage A once: load fp32, convert, swizzled write ----
#pragma unroll
  for (int p = 0; p < 8; ++p) {
    int e = p * 256 + t;
    int r = e >> 5, g = e & 31;                    // granule g = dims 8g..8g+7
    const float4* src = ((const float4*)(f + (size_t)(i0 + r) * DIM)) + g * 2;
    float4 x = src[0], y = src[1];
    ((uint4*)Ash)[r * 32 + (g ^ (r & 31))] = pack8(x, y);
  }

  const int w = t >> 6, lane = t & 63;
  const int ihalf = w >> 1, jhalf = w & 1;
  const int m15 = lane & 15, quad = lane >> 4;

  // top-8 list per thread: rows t>>2, cols segment (t&3)*16
  float mv[NCAND]; int mi[NCAND];
#pragma unroll
  for (int k = 0; k < NCAND; ++k) { mv[k] = -1e30f; mi[k] = -1; }

  // prefetch B tile 0
  float4 fr[16];
#pragma unroll
  for (int p = 0; p < 8; ++p) {
    int e = p * 256 + t;
    int r = e >> 5, g = e & 31;
    const float4* src = ((const float4*)(f + (size_t)(jbase + r) * DIM)) + g * 2;
    fr[2 * p] = src[0]; fr[2 * p + 1] = src[1];
  }

  for (int jt = 0; jt < JSPAN / 64; ++jt) {
    const int j0 = jt * 64;
    __syncthreads();  // (a) prev top-k reads done; A staged (first iter)
#pragma unroll
    for (int p = 0; p < 8; ++p) {
      int e = p * 256 + t;
      int r = e >> 5, g = e & 31;
      ((uint4*)Bsh)[r * 32 + (g ^ (r & 31))] = pack8(fr[2 * p], fr[2 * p + 1]);
    }
    __syncthreads();  // (b) B visible

    // prefetch next B while MFMA runs
    if (jt + 1 < JSPAN / 64) {
#pragma unroll
      for (int p = 0; p < 8; ++p) {
        int e = p * 256 + t;
        int r = e >> 5, g = e & 31;
        const float4* src =
            ((const float4*)(f + (size_t)(jbase + j0 + 64 + r) * DIM)) + g * 2;
        fr[2 * p] = src[0]; fr[2 * p + 1] = src[1];
      }
    }

    f32x4 acc[2][2];
#pragma unroll
    for (int si = 0; si < 2; ++si)
#pragma unroll
      for (int sj = 0; sj < 2; ++sj) acc[si][sj] = (f32x4)(0.f);

#pragma unroll
    for (int kc = 0; kc < 8; ++kc) {
      const int g = kc * 4 + quad;
      bf16x8 av[2], bv[2];
#pragma unroll
      for (int s = 0; s < 2; ++s) {
        int ra = ihalf * 32 + s * 16 + m15;
        av[s] = ((const bf16x8*)Ash)[ra * 32 + (g ^ (ra & 31))];
        int rb = jhalf * 32 + s * 16 + m15;
        bv[s] = ((const bf16x8*)Bsh)[rb * 32 + (g ^ (rb & 31))];
      }
      acc[0][0] = __builtin_amdgcn_mfma_f32_16x16x32_bf16(av[0], bv[0], acc[0][0], 0, 0, 0);
      acc[0][1] = __builtin_amdgcn_mfma_f32_16x16x32_bf16(av[0], bv[1], acc[0][1], 0, 0, 0);
      acc[1][0] = __builtin_amdgcn_mfma_f32_16x16x32_bf16(av[1], bv[0], acc[1][0], 0, 0, 0);
      acc[1][1] = __builtin_amdgcn_mfma_f32_16x16x32_bf16(av[1], bv[1], acc[1][1], 0, 0, 0);
    }

    // C -> swizzled LDS. C layout: col=lane&15, row=quad*4+reg.
#pragma unroll
    for (int si = 0; si < 2; ++si)
#pragma unroll
      for (int sj = 0; sj < 2; ++sj)
#pragma unroll
        for (int r = 0; r < 4; ++r) {
          int col = jhalf * 32 + sj * 16 + m15;
          int row = ihalf * 32 + si * 16 + quad * 4 + r;
          int gc = col >> 2, sg = gc ^ (row & 15);
          Csh[row * 64 + sg * 4 + (col & 3)] = acc[si][sj][r];
        }
    __syncthreads();  // (c) C visible

    // top-8 insert: thread -> (row t>>2, cols (t&3)*16 .. +15)
    {
      int row = t >> 2, q = t & 3;
#pragma unroll
      for (int p = 0; p < 4; ++p) {
        int gc = q * 4 + p, sg = gc ^ (row & 15);
        float4 v = *(const float4*)&Csh[row * 64 + sg * 4];
        int jg = jbase + j0 + gc * 4;
        float vv[4] = {v.x, v.y, v.z, v.w};
#pragma unroll
        for (int s = 0; s < 4; ++s) {
          float val = vv[s];
          if (val > mv[NCAND - 1]) {
            mv[NCAND - 1] = val; mi[NCAND - 1] = jg + s;
#pragma unroll
            for (int k = NCAND - 1; k >= 1; --k) {
              if (mv[k] > mv[k - 1]) {
                float tv = mv[k]; mv[k] = mv[k - 1]; mv[k - 1] = tv;
                int ti = mi[k]; mi[k] = mi[k - 1]; mi[k - 1] = ti;
              }
            }
          }
        }
      }
    }
  }

  // ---- merge 4 per-thread lists per row -> top-8 per (row, split) ----
  __syncthreads();
  float* mergeV = Csh;                 // [64][32] swizzled
  int*   mergeI = (int*)(Csh + 2048);  // [64][32] swizzled
  {
    int row = t >> 2, q = t & 3;
#pragma unroll
    for (int k = 0; k < NCAND; ++k) {
      int pos = q * NCAND + k;
      mergeV[row * 32 + (pos ^ (row & 31))] = mv[k];
      mergeI[row * 32 + (pos ^ (row & 31))] = mi[k];
    }
  }
  __syncthreads();
  if (t < 64) {
    float fv[NCAND]; int fi[NCAND];
#pragma unroll
    for (int k = 0; k < NCAND; ++k) { fv[k] = -1e30f; fi[k] = -1; }
    for (int s = 0; s < 32; ++s) {
      float v = mergeV[t * 32 + (s ^ (t & 31))];
      int j = mergeI[t * 32 + (s ^ (t & 31))];
      if (v > fv[NCAND - 1]) {
        fv[NCAND - 1] = v; fi[NCAND - 1] = j;
#pragma unroll
        for (int k = NCAND - 1; k >= 1; --k) {
          if (fv[k] > fv[k - 1]) {
            float tv = fv[k]; fv[k] = fv[k - 1]; fv[k - 1] = tv;
            int ti = fi[k]; fi[k] = fi[k - 1]; fi[k - 1] = ti;
          }
        }
      }
    }
#pragma unroll
    for (int k = 0; k < NCAND; ++k)
      candp[(size_t)js * (NROWS * NCAND) + (size_t)(i0 + t) * NCAND + k] = fi[k];
  }
}

// ---------------- 3. fp64 exact refine: 32 candidates -> exact top-5 ----------------
// 4 rows per block (one row per wave).
__global__ void k_refine(const float* __restrict__ f, const double* __restrict__ sqd,
                         const int* __restrict__ candp, int* __restrict__ nbr) {
  const int row = blockIdx.x * 4 + (threadIdx.x >> 6);
  const int t = threadIdx.x & 63;
  const int c = t >> 1;        // candidate 0..31
  const int seg = t & 1;       // half of D
  const int split = c >> 3, slot = c & 7;
  int j = candp[(size_t)split * (NROWS * NCAND) + (size_t)row * NCAND + slot];
  const float* fi = f + (size_t)row * DIM;
  const float* fj = f + (size_t)j * DIM;
  double dot = 0.0;
  const int dbase = seg * 128;
#pragma unroll 4
  for (int d = 0; d < 128; ++d)
    dot = fma((double)fi[dbase + d], (double)fj[dbase + d], dot);
  dot += __shfl_xor(dot, 1, 64);
  double key = sqd[j] - 2.0 * dot;   // == dist2 - sq_i (monotone in dist)
  bool valid = (seg == 0) && (j != row);   // exclude self (== reference idx[:,1:])
  for (int s = 0; s < KNN; ++s) {
    double v = valid ? key : (double)INFINITY;
    int vj = valid ? j : 0x7fffffff;
#pragma unroll
    for (int m = 1; m < 64; m <<= 1) {
      double ov = __shfl_xor(v, m, 64);
      int oj = __shfl_xor(vj, m, 64);
      if (ov < v || (ov == v && oj < vj)) { v = ov; vj = oj; }
    }
    if (valid && vj == j) valid = false;
    if (t == 0) nbr[(size_t)row * 8 + s] = vj;
  }
}

// ---------------- 4. unary + Y0 ----------------
__global__ void k_inity(const float* __restrict__ scores, float* __restrict__ unary,
                        float* __restrict__ Y) {
  int row = blockIdx.x * 4 + (threadIdx.x >> 6);
  int c = threadIdx.x & 63;
  float s = scores[(size_t)row * NCLS + c];
  float u = -logf(s + 1e-10f);
  unary[(size_t)row * NCLS + c] = u;
  float logit = -u;
  float m = wave_max64(logit);
  float e = expf(logit - m);
  float sum = wave_sum64(e);
  Y[(size_t)row * NCLS + c] = e / sum;
}

// ---------------- 5. mean-field iteration + fused convergence check ----------------
// E = sum(u*Y - pw*Y + Y*logY) collapses to -sum_rows lse (LAM == 1).
// Last-block-done pattern: per-iter counter; last block sums Epart
// deterministically and updates IterState.
__global__ void k_iter(const float* __restrict__ Yin, float* __restrict__ Yout,
                       const float* __restrict__ unary, const int* __restrict__ nbr,
                       IterState* st, double* __restrict__ Epart,
                       int* __restrict__ ctr, int iter) {
  if (st->flag) return;
  const int w = threadIdx.x >> 6;
  const int lane = threadIdx.x & 63;
  const int wid = blockIdx.x * 4 + w;
  double ew = 0.0;
#pragma unroll
  for (int r = 0; r < 4; ++r) {
    int row = wid * 4 + r;
    const int* nb = nbr + (size_t)row * 8;
    float pw = 0.f;
#pragma unroll
    for (int k = 0; k < KNN; ++k) pw += Yin[(size_t)nb[k] * NCLS + lane];
    float logit = pw - unary[(size_t)row * NCLS + lane];
    float m = wave_max64(logit);
    float e = expf(logit - m);
    float sum = wave_sum64(e);
    Yout[(size_t)row * NCLS + lane] = e / sum;
    ew += -(double)(m + logf(sum));
  }
  __shared__ double sE[4];
  __shared__ int isLast;
  if (lane == 0) sE[w] = ew;
  __syncthreads();
  if (threadIdx.x == 0) {
    Epart[blockIdx.x] = (sE[0] + sE[1]) + (sE[2] + sE[3]);
    __threadfence();
    int old = atomicAdd(&ctr[iter], 1);
    isLast = (old == ITER_GRID - 1);
  }
  __syncthreads();
  if (isLast) {
    __threadfence();  // acquire all Epart writes
    __shared__ double sd[256];
    double s = 0.0;
    for (int i = threadIdx.x; i < ITER_GRID; i += 256) s += Epart[i];
    sd[threadIdx.x] = s;
    __syncthreads();
    for (int off = 128; off >= 1; off >>= 1) {
      if (threadIdx.x < off) sd[threadIdx.x] += sd[threadIdx.x + off];
      __syncthreads();
    }
    if (threadIdx.x == 0) {
      double E = sd[0];
      bool conv = (iter > 1) && (fabs(E - st->Eold) <= 1e-8 * fabs(st->Eold));
      st->final_buf = (iter + 1) & 1;  // this iter wrote buf[(iter+1)&1]
      if (conv) st->flag = 1;
      else st->Eold = E;
    }
  }
}

// ---------------- 0/7. state init + final copy ----------------
__global__ void k_init(IterState* st, int* ctr) {
  int t = threadIdx.x;
  if (t < MAXSTEPS) ctr[t] = 0;
  if (t == 255) { st->Eold = (double)INFINITY; st->flag = 0; st->final_buf = 0; }
}
__global__ void k_copy(const float* __restrict__ Ya, const float* __restrict__ Yb,
                       const IterState* __restrict__ st, float* __restrict__ out) {
  const float* src = st->final_buf ? Yb : Ya;
  int i = blockIdx.x * blockDim.x + threadIdx.x;
  ((float4*)out)[i] = ((const float4*)src)[i];
}

extern "C" void kernel_launch(void* const* d_in, const int* in_sizes, int n_in,
                              void* d_out, int out_size, void* d_ws, size_t ws_size,
                              hipStream_t stream) {
  (void)in_sizes; (void)n_in; (void)out_size; (void)ws_size;
  const float* scores = (const float*)d_in[0];
  const float* feats  = (const float*)d_in[1];
  float* out = (float*)d_out;
  char* ws = (char*)d_ws;
  // workspace layout (all 256B-aligned); total ~15.4 MB
  float*  f     = (float*)(ws + 0);          //  8 MB
  float*  Ya    = (float*)(ws + 8388608);    //  2 MB
  float*  Yb    = (float*)(ws + 10485760);   //  2 MB
  float*  unary = (float*)(ws + 12582912);   //  2 MB
  double* sqd   = (double*)(ws + 14680064);  // 64 KB
  int*    candp = (int*)(ws + 14745600);     //  1 MB (4 splits x 8192 x 8)
  int*    nbr   = (int*)(ws + 15794176);     // 256 KB
  double* Epart = (double*)(ws + 16056320);  //  4 KB
  int*    ctr   = (int*)(ws + 16060416);     // 400 B
  IterState* st = (IterState*)(ws + 16061440);

  k_init<<<1, 256, 0, stream>>>(st, ctr);
  k_normalize<<<NROWS / 4, 256, 0, stream>>>(feats, f, sqd);
  k_gram<<<(NROWS / 64) * NSPLIT, 256, 0, stream>>>(f, candp);
  k_refine<<<NROWS / 4, 256, 0, stream>>>(f, sqd, candp, nbr);
  k_inity<<<NROWS / 4, 256, 0, stream>>>(scores, unary, Ya);
  for (int k = 0; k < MAXSTEPS; ++k) {
    const float* yin = (k & 1) ? Yb : Ya;
    float* yout = (k & 1) ? Ya : Yb;
    k_iter<<<ITER_GRID, 256, 0, stream>>>(yin, yout, unary, nbr, st, Epart, ctr, k);
  }
  k_copy<<<512, 256, 0, stream>>>(Ya, Yb, st, out);
}